// Round 4
// baseline (206.374 us; speedup 1.0000x reference)
//
#include <hip/hip_runtime.h>
#include <hip/hip_bf16.h>
#include <stdint.h>

#define M_DIM 8192
#define K_DIM 4096
#define N_DIM 4096

#define BM 256
#define BN 256
#define BKB 64              // K-bytes (=i8 elems) per tile
#define NT (K_DIM / BKB)    // 64 K-tiles
#define ATILE (BM * BKB)    // 16384 B
#define TBYTES (ATILE + BN * BKB)   // 32768 B per K-tile buffer

typedef int i32x4 __attribute__((ext_vector_type(4)));

// ---------------------------------------------------------------------------
// Kernel 1: per-tensor activation quantization f32 -> i8 (unchanged, passing)
// ---------------------------------------------------------------------------
__global__ __launch_bounds__(256) void quant_x_kernel(
    const float* __restrict__ x, const float* __restrict__ scale_p,
    const int* __restrict__ off_p, int8_t* __restrict__ xq)
{
    const float s = scale_p[0];
    const float off = (float)off_p[0];
    long base = ((long)blockIdx.x * 256 + threadIdx.x) * 16;
    const float4* xin = (const float4*)(x + base);
    float v[16];
    *(float4*)(v + 0)  = xin[0];
    *(float4*)(v + 4)  = xin[1];
    *(float4*)(v + 8)  = xin[2];
    *(float4*)(v + 12) = xin[3];
    uint32_t pk[4];
#pragma unroll
    for (int g = 0; g < 4; ++g) {
        uint32_t p = 0;
#pragma unroll
        for (int j = 0; j < 4; ++j) {
            float q = rintf(v[g * 4 + j] / s) + off;
            q = fminf(fmaxf(q, -128.0f), 127.0f);
            int qi = (int)q;
            p |= ((uint32_t)(qi & 0xff)) << (8 * j);
        }
        pk[g] = p;
    }
    uint4 o; o.x = pk[0]; o.y = pk[1]; o.z = pk[2]; o.w = pk[3];
    *(uint4*)(xq + base) = o;
}

// ---------------------------------------------------------------------------
// Kernel 2: weight pack + permutation fold (unchanged, passing)
// ---------------------------------------------------------------------------
__global__ __launch_bounds__(256) void pack_w_kernel(
    const int* __restrict__ w, const int* __restrict__ index,
    const float* __restrict__ deq, const int* __restrict__ qb,
    int8_t* __restrict__ bp, float* __restrict__ dsp, int* __restrict__ qbp)
{
    int j = blockIdx.x;
    int t = threadIdx.x;
    int src = index[j];
    const int4* wrow = (const int4*)(w + (long)src * K_DIM);
    uint32_t pk[4];
#pragma unroll
    for (int g = 0; g < 4; ++g) {
        int4 c = wrow[t * 4 + g];
        pk[g] = ((uint32_t)(c.x & 0xff)) | (((uint32_t)(c.y & 0xff)) << 8) |
                (((uint32_t)(c.z & 0xff)) << 16) | (((uint32_t)(c.w & 0xff)) << 24);
    }
    uint4 o; o.x = pk[0]; o.y = pk[1]; o.z = pk[2]; o.w = pk[3];
    *(uint4*)(bp + (long)j * K_DIM + t * 16) = o;
    if (t == 0) { dsp[j] = deq[src]; qbp[j] = qb[src]; }
}

// ---------------------------------------------------------------------------
// Kernel 3: 256x256 int8 GEMM with register-level fragment double-buffering.
// Ring-of-4 LDS buffers (128KB), stage distance 3, frag-read distance 1.
// Per tile t: {ds_read frags(t+1)->setW || stage(t+3)} -> MFMA on setR
// (frags read LAST tile; lgkm latency hidden under previous MFMA cluster)
// -> vmcnt(4) -> barrier.
// Safety invariants (by induction from prologue):
//  - at barrier entering tile t, tile t+1 is resident (end-of-(t-1) vmcnt(4)
//    leaves only (t+2)'s 4 loads in flight) -> frag reads of t+1 are safe.
//  - staging t+3 overwrites buffer (t-1)%4, whose frag reads were drained
//    (compiler lgkm before tile t-1's MFMAs) before the end-of-(t-1) barrier.
// All buffer indices and frag-set selection are compile-time (static x4
// unroll + static tail) -> everything stays in registers.
// ---------------------------------------------------------------------------
__device__ __forceinline__ void gload_lds16(const int8_t* g, int8_t* l)
{
    __builtin_amdgcn_global_load_lds(
        (const __attribute__((address_space(1))) uint32_t*)g,
        (__attribute__((address_space(3))) uint32_t*)l, 16, 0, 0);
}

__global__ __launch_bounds__(512, 2) void gemm_i8_kernel(
    const int8_t* __restrict__ A, const int8_t* __restrict__ B,
    const float* __restrict__ dsp, const int* __restrict__ qbp,
    float* __restrict__ C)
{
    __shared__ int8_t lds[4][TBYTES];   // 128 KB

    // XCD-aware bijective swizzle (grid = 512, divisible by 8)
    int bid = blockIdx.x;
    int swz = (bid & 7) * (gridDim.x >> 3) + (bid >> 3);
    int bm = swz & 31;              // M/BM = 32
    int bn = swz >> 5;              // N/BN = 16
    int brow = bm * BM, bcol = bn * BN;

    int t = threadIdx.x;
    int wv = t >> 6;
    int l  = t & 63;
    int lr = l & 15;                // row within 16x16 fragment
    int ls = l >> 4;                // logical 16B k-slot
    int wrM = (wv >> 2) * 128;      // wave row offset (2 M-waves)
    int wcN = (wv & 3) * 64;        // wave col offset (4 N-waves)
    int pslot = ls ^ ((lr >> 1) & 3);   // swizzled physical slot (lane-const)

    const int aL = (wrM + lr) * BKB + pslot * 16;           // A frag base
    const int bL = ATILE + (wcN + lr) * BKB + pslot * 16;   // B frag base

    // Staging: 2 A-chunks + 2 B-chunks (16B each) per thread per K-tile.
    // Linear LDS dest; global source pre-swizzled (slot = (ca&3)^((row>>1)&3)).
    int ca0 = t, ca1 = 512 + t;
    int r0 = ca0 >> 2, r1 = ca1 >> 2;
    const int8_t* sa0 = A + (long)(brow + r0) * K_DIM + ((ca0 & 3) ^ ((r0 >> 1) & 3)) * 16;
    const int8_t* sa1 = A + (long)(brow + r1) * K_DIM + ((ca1 & 3) ^ ((r1 >> 1) & 3)) * 16;
    const int8_t* sb0 = B + (long)(bcol + r0) * K_DIM + ((ca0 & 3) ^ ((r0 >> 1) & 3)) * 16;
    const int8_t* sb1 = B + (long)(bcol + r1) * K_DIM + ((ca1 & 3) ^ ((r1 >> 1) & 3)) * 16;
    const int da0 = ca0 * 16, da1 = ca1 * 16;
    const int db0 = ATILE + ca0 * 16, db1 = ATILE + ca1 * 16;

#define STAGE(SBUF) do { \
        int8_t* _d = &lds[SBUF][0]; \
        gload_lds16(sa0, _d + da0); \
        gload_lds16(sa1, _d + da1); \
        gload_lds16(sb0, _d + db0); \
        gload_lds16(sb1, _d + db1); \
        sa0 += BKB; sa1 += BKB; sb0 += BKB; sb1 += BKB; \
    } while (0)

#define FRAG_READ(AF, BF, RBUF) do { \
        const int8_t* _b = &lds[RBUF][0]; \
        _Pragma("unroll") \
        for (int n = 0; n < 4; ++n) BF[n] = *(const i32x4*)(_b + bL + n * 1024); \
        _Pragma("unroll") \
        for (int m = 0; m < 8; ++m) AF[m] = *(const i32x4*)(_b + aL + m * 1024); \
    } while (0)

#define MFMA32(AF, BF) do { \
        __builtin_amdgcn_s_setprio(1); \
        _Pragma("unroll") \
        for (int m = 0; m < 8; ++m) \
        _Pragma("unroll") \
        for (int n = 0; n < 4; ++n) \
            acc[m][n] = __builtin_amdgcn_mfma_i32_16x16x64_i8(AF[m], BF[n], acc[m][n], 0, 0, 0); \
        __builtin_amdgcn_s_setprio(0); \
    } while (0)

#define TILE_END(VMC) do { \
        __builtin_amdgcn_sched_barrier(0); \
        asm volatile("s_waitcnt vmcnt(" #VMC ")" ::: "memory"); \
        asm volatile("s_barrier" ::: "memory"); \
    } while (0)

    // Prologue: stage tiles 0,1,2 into buffers 0,1,2
    STAGE(0); STAGE(1); STAGE(2);
    asm volatile("s_waitcnt vmcnt(4)" ::: "memory");   // tiles 0,1 resident
    asm volatile("s_barrier" ::: "memory");

    i32x4 afA[8], bfA[4], afB[8], bfB[4];
    i32x4 acc[8][4] = {};

    FRAG_READ(afA, bfA, 0);                            // tile 0 frags -> set A

    // Main loop: kt = 0..59, static x4 unroll (buffer ring period 4,
    // frag-set period 2). Every position: read t+1, stage t+3 (both < NT).
    for (int it = 0; it < 15; ++it) {
        // kt % 4 == 0: compute A, read buf1 -> B, stage buf3
        FRAG_READ(afB, bfB, 1); STAGE(3);
        __builtin_amdgcn_sched_barrier(0);
        MFMA32(afA, bfA);
        TILE_END(4);
        // kt % 4 == 1: compute B, read buf2 -> A, stage buf0
        FRAG_READ(afA, bfA, 2); STAGE(0);
        __builtin_amdgcn_sched_barrier(0);
        MFMA32(afB, bfB);
        TILE_END(4);
        // kt % 4 == 2: compute A, read buf3 -> B, stage buf1
        FRAG_READ(afB, bfB, 3); STAGE(1);
        __builtin_amdgcn_sched_barrier(0);
        MFMA32(afA, bfA);
        TILE_END(4);
        // kt % 4 == 3: compute B, read buf0 -> A, stage buf2
        FRAG_READ(afA, bfA, 0); STAGE(2);
        __builtin_amdgcn_sched_barrier(0);
        MFMA32(afB, bfB);
        TILE_END(4);
    }

    // Static tail: kt = 60, 61, 62, 63 (60 % 4 == 0)
    // kt=60: read 61 (buf1), stage 63 (buf3)
    FRAG_READ(afB, bfB, 1); STAGE(3);
    __builtin_amdgcn_sched_barrier(0);
    MFMA32(afA, bfA);
    TILE_END(4);
    // kt=61: read 62 (buf2), no stage; end must drain tile 63's loads
    FRAG_READ(afA, bfA, 2);
    __builtin_amdgcn_sched_barrier(0);
    MFMA32(afB, bfB);
    TILE_END(0);
    // kt=62: read 63 (buf3), no stage, no barrier needed after
    FRAG_READ(afB, bfB, 3);
    __builtin_amdgcn_sched_barrier(0);
    MFMA32(afA, bfA);
    // kt=63: compute final set
    MFMA32(afB, bfB);

#undef STAGE
#undef FRAG_READ
#undef MFMA32
#undef TILE_END

    // Epilogue: C/D layout col = lane&15, row = (lane>>4)*4 + reg
#pragma unroll
    for (int n = 0; n < 4; ++n) {
        int gc = bcol + wcN + n * 16 + lr;
        float ds = dsp[gc];
        int qb = qbp[gc];
#pragma unroll
        for (int m = 0; m < 8; ++m) {
            int gr0 = brow + wrM + m * 16 + ls * 4;
#pragma unroll
            for (int r = 0; r < 4; ++r) {
                C[(long)(gr0 + r) * N_DIM + gc] = (float)(acc[m][n][r] + qb) * ds;
            }
        }
    }
}

// ---------------------------------------------------------------------------
extern "C" void kernel_launch(void* const* d_in, const int* in_sizes, int n_in,
                              void* d_out, int out_size, void* d_ws, size_t ws_size,
                              hipStream_t stream)
{
    (void)in_sizes; (void)n_in; (void)out_size; (void)ws_size;
    const float* x   = (const float*)d_in[0];
    const int*   w   = (const int*)d_in[1];
    const float* is  = (const float*)d_in[2];
    const int*   io  = (const int*)d_in[3];
    const float* dq  = (const float*)d_in[4];
    const int*   qb  = (const int*)d_in[5];
    const int*   idx = (const int*)d_in[6];
    float* out = (float*)d_out;

    int8_t* xq  = (int8_t*)d_ws;                           // 33554432 B
    int8_t* bp  = xq + (size_t)M_DIM * K_DIM;              // 16777216 B
    float*  dsp = (float*)(bp + (size_t)N_DIM * K_DIM);    // 16384 B
    int*    qbp = (int*)(dsp + N_DIM);                     // 16384 B

    long quant_blocks = ((long)M_DIM * K_DIM) / 16 / 256;  // 8192
    quant_x_kernel<<<(int)quant_blocks, 256, 0, stream>>>(x, is, io, xq);
    pack_w_kernel<<<N_DIM, 256, 0, stream>>>(w, idx, dq, qb, bp, dsp, qbp);
    gemm_i8_kernel<<<(M_DIM / BM) * (N_DIM / BN), 512, 0, stream>>>(xq, bp, dsp, qbp, out);
}

// Round 5
// 201.066 us; speedup vs baseline: 1.0264x; 1.0264x over previous
//
#include <hip/hip_runtime.h>
#include <hip/hip_bf16.h>
#include <stdint.h>

#define M_DIM 8192
#define K_DIM 4096
#define N_DIM 4096

#define BM 256
#define BN 256
#define BKB 64              // K-bytes (=i8 elems) per tile
#define NT (K_DIM / BKB)    // 64 K-tiles
#define ATILE (BM * BKB)    // 16384 B
#define TBYTES (ATILE + BN * BKB)   // 32768 B per K-tile buffer

typedef int i32x4 __attribute__((ext_vector_type(4)));

// ---------------------------------------------------------------------------
// Kernel 1: per-tensor activation quantization f32 -> i8 (unchanged, passing)
// ---------------------------------------------------------------------------
__global__ __launch_bounds__(256) void quant_x_kernel(
    const float* __restrict__ x, const float* __restrict__ scale_p,
    const int* __restrict__ off_p, int8_t* __restrict__ xq)
{
    const float s = scale_p[0];
    const float off = (float)off_p[0];
    long base = ((long)blockIdx.x * 256 + threadIdx.x) * 16;
    const float4* xin = (const float4*)(x + base);
    float v[16];
    *(float4*)(v + 0)  = xin[0];
    *(float4*)(v + 4)  = xin[1];
    *(float4*)(v + 8)  = xin[2];
    *(float4*)(v + 12) = xin[3];
    uint32_t pk[4];
#pragma unroll
    for (int g = 0; g < 4; ++g) {
        uint32_t p = 0;
#pragma unroll
        for (int j = 0; j < 4; ++j) {
            float q = rintf(v[g * 4 + j] / s) + off;
            q = fminf(fmaxf(q, -128.0f), 127.0f);
            int qi = (int)q;
            p |= ((uint32_t)(qi & 0xff)) << (8 * j);
        }
        pk[g] = p;
    }
    uint4 o; o.x = pk[0]; o.y = pk[1]; o.z = pk[2]; o.w = pk[3];
    *(uint4*)(xq + base) = o;
}

// ---------------------------------------------------------------------------
// Kernel 2: weight pack + permutation fold (unchanged, passing)
// ---------------------------------------------------------------------------
__global__ __launch_bounds__(256) void pack_w_kernel(
    const int* __restrict__ w, const int* __restrict__ index,
    const float* __restrict__ deq, const int* __restrict__ qb,
    int8_t* __restrict__ bp, float* __restrict__ dsp, int* __restrict__ qbp)
{
    int j = blockIdx.x;
    int t = threadIdx.x;
    int src = index[j];
    const int4* wrow = (const int4*)(w + (long)src * K_DIM);
    uint32_t pk[4];
#pragma unroll
    for (int g = 0; g < 4; ++g) {
        int4 c = wrow[t * 4 + g];
        pk[g] = ((uint32_t)(c.x & 0xff)) | (((uint32_t)(c.y & 0xff)) << 8) |
                (((uint32_t)(c.z & 0xff)) << 16) | (((uint32_t)(c.w & 0xff)) << 24);
    }
    uint4 o; o.x = pk[0]; o.y = pk[1]; o.z = pk[2]; o.w = pk[3];
    *(uint4*)(bp + (long)j * K_DIM + t * 16) = o;
    if (t == 0) { dsp[j] = deq[src]; qbp[j] = qb[src]; }
}

// ---------------------------------------------------------------------------
// Kernel 3: 256x256 int8 GEMM, m201-faithful fine-phase schedule.
// 8 waves (2M x 4N), wave tile 128x64, ring-of-3 LDS buffers (96KB).
// Per K-tile: 4 phases, each {frag ds_reads for one C-quadrant || 1
// global_load_lds of tile t+2 -> s_barrier -> lgkmcnt(0)+sched_barrier ->
// setprio(1) 8 MFMA setprio(0) -> s_barrier}. Counted vmcnt(4) ONCE per
// K-tile (end of phase 3) — tile t+2's 4 loads stay in flight across all
// barriers; tile t+1 resident for every wave entering tile t+1.
// Small MFMA clusters + per-phase barriers keep waves' DS and MFMA phases
// interleaved across the CU (m196/m233: the fine interleave is the lever).
// ---------------------------------------------------------------------------
__device__ __forceinline__ void gload_lds16(const int8_t* g, int8_t* l)
{
    __builtin_amdgcn_global_load_lds(
        (const __attribute__((address_space(1))) uint32_t*)g,
        (__attribute__((address_space(3))) uint32_t*)l, 16, 0, 0);
}

__global__ __launch_bounds__(512, 2) void gemm_i8_kernel(
    const int8_t* __restrict__ A, const int8_t* __restrict__ B,
    const float* __restrict__ dsp, const int* __restrict__ qbp,
    float* __restrict__ C)
{
    __shared__ int8_t lds[3][TBYTES];   // 96 KB

    // XCD-aware bijective swizzle (grid = 512, divisible by 8)
    int bid = blockIdx.x;
    int swz = (bid & 7) * (gridDim.x >> 3) + (bid >> 3);
    int bm = swz & 31;              // M/BM = 32
    int bn = swz >> 5;              // N/BN = 16
    int brow = bm * BM, bcol = bn * BN;

    int t = threadIdx.x;
    int wv = t >> 6;
    int l  = t & 63;
    int lr = l & 15;                // row within 16x16 fragment
    int ls = l >> 4;                // logical 16B k-slot
    int wrM = (wv >> 2) * 128;      // wave row offset (2 M-waves)
    int wcN = (wv & 3) * 64;        // wave col offset (4 N-waves)
    int pslot = ls ^ ((lr >> 1) & 3);   // swizzled physical slot (lane-const)

    // ds_read byte offsets within a K-tile buffer
    int aoff[8], boff[4];
#pragma unroll
    for (int m = 0; m < 8; ++m)
        aoff[m] = (wrM + m * 16 + lr) * BKB + pslot * 16;
#pragma unroll
    for (int n = 0; n < 4; ++n)
        boff[n] = ATILE + (wcN + n * 16 + lr) * BKB + pslot * 16;

    // Staging: 2 A-chunks + 2 B-chunks (16B each) per thread per K-tile.
    // Linear LDS dest; global source pre-swizzled (slot = (ca&3)^((row>>1)&3)).
    int ca0 = t, ca1 = 512 + t;
    int r0 = ca0 >> 2, r1 = ca1 >> 2;
    const int8_t* sa0 = A + (long)(brow + r0) * K_DIM + ((ca0 & 3) ^ ((r0 >> 1) & 3)) * 16;
    const int8_t* sa1 = A + (long)(brow + r1) * K_DIM + ((ca1 & 3) ^ ((r1 >> 1) & 3)) * 16;
    const int8_t* sb0 = B + (long)(bcol + r0) * K_DIM + ((ca0 & 3) ^ ((r0 >> 1) & 3)) * 16;
    const int8_t* sb1 = B + (long)(bcol + r1) * K_DIM + ((ca1 & 3) ^ ((r1 >> 1) & 3)) * 16;
    const int da0 = ca0 * 16, da1 = ca1 * 16;
    const int db0 = ATILE + ca0 * 16, db1 = ATILE + ca1 * 16;

#define LGKM0_FENCE() do { \
        asm volatile("s_waitcnt lgkmcnt(0)" ::: "memory"); \
        __builtin_amdgcn_sched_barrier(0); \
    } while (0)

#define MFMA8(MLO, NLO) do { \
        __builtin_amdgcn_s_setprio(1); \
        _Pragma("unroll") \
        for (int m = 0; m < 4; ++m) \
        _Pragma("unroll") \
        for (int n = 0; n < 2; ++n) \
            acc[(MLO) + m][(NLO) + n] = __builtin_amdgcn_mfma_i32_16x16x64_i8( \
                af[(MLO) + m], bf[(NLO) + n], acc[(MLO) + m][(NLO) + n], 0, 0, 0); \
        __builtin_amdgcn_s_setprio(0); \
    } while (0)

    // Prologue: stage tiles 0 and 1 into buffers 0 and 1
#pragma unroll
    for (int p = 0; p < 2; ++p) {
        int8_t* d = &lds[p][0];
        gload_lds16(sa0, d + da0);
        gload_lds16(sa1, d + da1);
        gload_lds16(sb0, d + db0);
        gload_lds16(sb1, d + db1);
        sa0 += BKB; sa1 += BKB; sb0 += BKB; sb1 += BKB;
    }
    asm volatile("s_waitcnt vmcnt(4)" ::: "memory");   // tile 0 resident
    __builtin_amdgcn_s_barrier();

    i32x4 acc[8][4] = {};
    int cur = 0, stg = 2;

    for (int kt = 0; kt < NT; ++kt) {
        const bool do_stage = (kt + 2) < NT;
        const int8_t* base = lds[cur];
        int8_t* sdst = lds[stg];

        i32x4 af[8], bf[4];

        // ---- phase 0: reads {bf0,bf1, af0..3}, stage A-chunk0, MFMA Q(0,0)
        bf[0] = *(const i32x4*)(base + boff[0]);
        bf[1] = *(const i32x4*)(base + boff[1]);
#pragma unroll
        for (int m = 0; m < 4; ++m) af[m] = *(const i32x4*)(base + aoff[m]);
        if (do_stage) { gload_lds16(sa0, sdst + da0); sa0 += BKB; }
        __builtin_amdgcn_s_barrier();
        LGKM0_FENCE();
        MFMA8(0, 0);
        __builtin_amdgcn_s_barrier();

        // ---- phase 1: reads {bf2,bf3}, stage A-chunk1, MFMA Q(0,2)
        bf[2] = *(const i32x4*)(base + boff[2]);
        bf[3] = *(const i32x4*)(base + boff[3]);
        if (do_stage) { gload_lds16(sa1, sdst + da1); sa1 += BKB; }
        __builtin_amdgcn_s_barrier();
        LGKM0_FENCE();
        MFMA8(0, 2);
        __builtin_amdgcn_s_barrier();

        // ---- phase 2: reads {af4..7}, stage B-chunk0, MFMA Q(4,0)
#pragma unroll
        for (int m = 4; m < 8; ++m) af[m] = *(const i32x4*)(base + aoff[m]);
        if (do_stage) { gload_lds16(sb0, sdst + db0); sb0 += BKB; }
        __builtin_amdgcn_s_barrier();
        LGKM0_FENCE();
        MFMA8(4, 0);
        __builtin_amdgcn_s_barrier();

        // ---- phase 3: no reads, stage B-chunk1, MFMA Q(4,2), tile-end vmcnt
        if (do_stage) { gload_lds16(sb1, sdst + db1); sb1 += BKB; }
        __builtin_amdgcn_s_barrier();
        __builtin_amdgcn_sched_barrier(0);
        MFMA8(4, 2);
        __builtin_amdgcn_sched_barrier(0);
        if (do_stage) asm volatile("s_waitcnt vmcnt(4)" ::: "memory");
        else          asm volatile("s_waitcnt vmcnt(0)" ::: "memory");
        __builtin_amdgcn_s_barrier();

        cur = (cur == 2) ? 0 : cur + 1;
        stg = (stg == 2) ? 0 : stg + 1;
    }

#undef LGKM0_FENCE
#undef MFMA8

    // Epilogue: C/D layout col = lane&15, row = (lane>>4)*4 + reg
#pragma unroll
    for (int n = 0; n < 4; ++n) {
        int gc = bcol + wcN + n * 16 + lr;
        float ds = dsp[gc];
        int qb = qbp[gc];
#pragma unroll
        for (int m = 0; m < 8; ++m) {
            int gr0 = brow + wrM + m * 16 + ls * 4;
#pragma unroll
            for (int r = 0; r < 4; ++r) {
                C[(long)(gr0 + r) * N_DIM + gc] = (float)(acc[m][n][r] + qb) * ds;
            }
        }
    }
}

// ---------------------------------------------------------------------------
extern "C" void kernel_launch(void* const* d_in, const int* in_sizes, int n_in,
                              void* d_out, int out_size, void* d_ws, size_t ws_size,
                              hipStream_t stream)
{
    (void)in_sizes; (void)n_in; (void)out_size; (void)ws_size;
    const float* x   = (const float*)d_in[0];
    const int*   w   = (const int*)d_in[1];
    const float* is  = (const float*)d_in[2];
    const int*   io  = (const int*)d_in[3];
    const float* dq  = (const float*)d_in[4];
    const int*   qb  = (const int*)d_in[5];
    const int*   idx = (const int*)d_in[6];
    float* out = (float*)d_out;

    int8_t* xq  = (int8_t*)d_ws;                           // 33554432 B
    int8_t* bp  = xq + (size_t)M_DIM * K_DIM;              // 16777216 B
    float*  dsp = (float*)(bp + (size_t)N_DIM * K_DIM);    // 16384 B
    int*    qbp = (int*)(dsp + N_DIM);                     // 16384 B

    long quant_blocks = ((long)M_DIM * K_DIM) / 16 / 256;  // 8192
    quant_x_kernel<<<(int)quant_blocks, 256, 0, stream>>>(x, is, io, xq);
    pack_w_kernel<<<N_DIM, 256, 0, stream>>>(w, idx, dq, qb, bp, dsp, qbp);
    gemm_i8_kernel<<<(M_DIM / BM) * (N_DIM / BN), 512, 0, stream>>>(xq, bp, dsp, qbp, out);
}

// Round 6
// 198.086 us; speedup vs baseline: 1.0418x; 1.0150x over previous
//
#include <hip/hip_runtime.h>
#include <hip/hip_bf16.h>
#include <stdint.h>

#define M_DIM 8192
#define K_DIM 4096
#define N_DIM 4096

#define BM 256
#define BN 256
#define BKB 64              // K-bytes (=i8 elems) per tile
#define NT (K_DIM / BKB)    // 64 K-tiles
#define ATILE (BM * BKB)    // 16384 B
#define TBYTES (ATILE + BN * BKB)   // 32768 B per K-tile buffer

typedef int i32x4 __attribute__((ext_vector_type(4)));

// ---------------------------------------------------------------------------
// Kernel 1: per-tensor activation quantization f32 -> i8 (unchanged, passing)
// ---------------------------------------------------------------------------
__global__ __launch_bounds__(256) void quant_x_kernel(
    const float* __restrict__ x, const float* __restrict__ scale_p,
    const int* __restrict__ off_p, int8_t* __restrict__ xq)
{
    const float s = scale_p[0];
    const float off = (float)off_p[0];
    long base = ((long)blockIdx.x * 256 + threadIdx.x) * 16;
    const float4* xin = (const float4*)(x + base);
    float v[16];
    *(float4*)(v + 0)  = xin[0];
    *(float4*)(v + 4)  = xin[1];
    *(float4*)(v + 8)  = xin[2];
    *(float4*)(v + 12) = xin[3];
    uint32_t pk[4];
#pragma unroll
    for (int g = 0; g < 4; ++g) {
        uint32_t p = 0;
#pragma unroll
        for (int j = 0; j < 4; ++j) {
            float q = rintf(v[g * 4 + j] / s) + off;
            q = fminf(fmaxf(q, -128.0f), 127.0f);
            int qi = (int)q;
            p |= ((uint32_t)(qi & 0xff)) << (8 * j);
        }
        pk[g] = p;
    }
    uint4 o; o.x = pk[0]; o.y = pk[1]; o.z = pk[2]; o.w = pk[3];
    *(uint4*)(xq + base) = o;
}

// ---------------------------------------------------------------------------
// Kernel 2: weight pack + permutation fold (unchanged, passing)
// ---------------------------------------------------------------------------
__global__ __launch_bounds__(256) void pack_w_kernel(
    const int* __restrict__ w, const int* __restrict__ index,
    const float* __restrict__ deq, const int* __restrict__ qb,
    int8_t* __restrict__ bp, float* __restrict__ dsp, int* __restrict__ qbp)
{
    int j = blockIdx.x;
    int t = threadIdx.x;
    int src = index[j];
    const int4* wrow = (const int4*)(w + (long)src * K_DIM);
    uint32_t pk[4];
#pragma unroll
    for (int g = 0; g < 4; ++g) {
        int4 c = wrow[t * 4 + g];
        pk[g] = ((uint32_t)(c.x & 0xff)) | (((uint32_t)(c.y & 0xff)) << 8) |
                (((uint32_t)(c.z & 0xff)) << 16) | (((uint32_t)(c.w & 0xff)) << 24);
    }
    uint4 o; o.x = pk[0]; o.y = pk[1]; o.z = pk[2]; o.w = pk[3];
    *(uint4*)(bp + (long)j * K_DIM + t * 16) = o;
    if (t == 0) { dsp[j] = deq[src]; qbp[j] = qb[src]; }
}

// ---------------------------------------------------------------------------
// Kernel 3: 256x256 int8 GEMM, single-barrier-per-K-tile, COMPILER-SCHEDULED
// DS->MFMA overlap. Per K-tile: {4 global_load_lds of tile t+2 (issued
// first) -> 12 ds_read_b128 -> 32 MFMA with compiler-emitted counted
// lgkmcnt waits interleaving reads and MFMAs} -> lgkmcnt(0) (free: placed
// AFTER the MFMAs, pins the buffer-reuse invariant even if the compiler
// sinks register-only MFMAs past the barrier asm) -> vmcnt(4) -> s_barrier.
// NO lgkm0/sched_barrier fence between ds_reads and MFMAs (R2-R5 mistake:
// it serialized the DS and MFMA pipes; counters showed exactly additive
// DS+MFMA time). Ring-of-3 LDS buffers; safety invariants as in R3.
// ---------------------------------------------------------------------------
__device__ __forceinline__ void gload_lds16(const int8_t* g, int8_t* l)
{
    __builtin_amdgcn_global_load_lds(
        (const __attribute__((address_space(1))) uint32_t*)g,
        (__attribute__((address_space(3))) uint32_t*)l, 16, 0, 0);
}

__global__ __launch_bounds__(512, 2) void gemm_i8_kernel(
    const int8_t* __restrict__ A, const int8_t* __restrict__ B,
    const float* __restrict__ dsp, const int* __restrict__ qbp,
    float* __restrict__ C)
{
    __shared__ int8_t lds[3][TBYTES];   // 96 KB

    // XCD-aware bijective swizzle (grid = 512, divisible by 8)
    int bid = blockIdx.x;
    int swz = (bid & 7) * (gridDim.x >> 3) + (bid >> 3);
    int bm = swz & 31;              // M/BM = 32
    int bn = swz >> 5;              // N/BN = 16
    int brow = bm * BM, bcol = bn * BN;

    int t = threadIdx.x;
    int wv = t >> 6;
    int l  = t & 63;
    int lr = l & 15;                // row within 16x16 fragment
    int ls = l >> 4;                // logical 16B k-slot
    int wrM = (wv >> 2) * 128;      // wave row offset (2 M-waves)
    int wcN = (wv & 3) * 64;        // wave col offset (4 N-waves)
    int pslot = ls ^ ((lr >> 1) & 3);   // swizzled physical slot (lane-const)

    // ds_read byte offsets within a K-tile buffer
    int aoff[8], boff[4];
#pragma unroll
    for (int m = 0; m < 8; ++m)
        aoff[m] = (wrM + m * 16 + lr) * BKB + pslot * 16;
#pragma unroll
    for (int n = 0; n < 4; ++n)
        boff[n] = ATILE + (wcN + n * 16 + lr) * BKB + pslot * 16;

    // Staging: 2 A-chunks + 2 B-chunks (16B each) per thread per K-tile.
    // Linear LDS dest; global source pre-swizzled (slot = (ca&3)^((row>>1)&3)).
    int ca0 = t, ca1 = 512 + t;
    int r0 = ca0 >> 2, r1 = ca1 >> 2;
    const int8_t* sa0 = A + (long)(brow + r0) * K_DIM + ((ca0 & 3) ^ ((r0 >> 1) & 3)) * 16;
    const int8_t* sa1 = A + (long)(brow + r1) * K_DIM + ((ca1 & 3) ^ ((r1 >> 1) & 3)) * 16;
    const int8_t* sb0 = B + (long)(bcol + r0) * K_DIM + ((ca0 & 3) ^ ((r0 >> 1) & 3)) * 16;
    const int8_t* sb1 = B + (long)(bcol + r1) * K_DIM + ((ca1 & 3) ^ ((r1 >> 1) & 3)) * 16;
    const int da0 = ca0 * 16, da1 = ca1 * 16;
    const int db0 = ATILE + ca0 * 16, db1 = ATILE + ca1 * 16;

    // Prologue: stage tiles 0 and 1 into buffers 0 and 1
#pragma unroll
    for (int p = 0; p < 2; ++p) {
        int8_t* d = &lds[p][0];
        gload_lds16(sa0, d + da0);
        gload_lds16(sa1, d + da1);
        gload_lds16(sb0, d + db0);
        gload_lds16(sb1, d + db1);
        sa0 += BKB; sa1 += BKB; sb0 += BKB; sb1 += BKB;
    }
    asm volatile("s_waitcnt vmcnt(4)" ::: "memory");   // tile 0 resident
    __builtin_amdgcn_s_barrier();

    i32x4 acc[8][4] = {};
    int cur = 0, stg = 2;

    for (int kt = 0; kt < NT; ++kt) {
        const bool do_stage = (kt + 2) < NT;
        const int8_t* base = lds[cur];

        // Prefetch loads for tile t+2 first (VMEM pipe, max flight time).
        if (do_stage) {
            int8_t* sdst = lds[stg];
            gload_lds16(sa0, sdst + da0);
            gload_lds16(sa1, sdst + da1);
            gload_lds16(sb0, sdst + db0);
            gload_lds16(sb1, sdst + db1);
            sa0 += BKB; sa1 += BKB; sb0 += BKB; sb1 += BKB;
        }

        // Fragment reads + MFMAs: NO fence between them — the compiler
        // tracks the register dependencies and emits counted lgkmcnt so
        // MFMAs start while later reads are still in flight (DS pipe and
        // MFMA pipe overlap within the wave).
        i32x4 af[8], bf[4];
#pragma unroll
        for (int n = 0; n < 4; ++n) bf[n] = *(const i32x4*)(base + boff[n]);
#pragma unroll
        for (int m = 0; m < 8; ++m) af[m] = *(const i32x4*)(base + aoff[m]);

#pragma unroll
        for (int m = 0; m < 8; ++m)
#pragma unroll
            for (int n = 0; n < 4; ++n)
                acc[m][n] = __builtin_amdgcn_mfma_i32_16x16x64_i8(
                    af[m], bf[n], acc[m][n], 0, 0, 0);

        // Tile end: lgkm drain is free here (all reads already consumed by
        // the MFMAs above) but guarantees no read of buffer `cur` is still
        // outstanding when it gets overwritten after the barrier. Counted
        // vmcnt leaves only tile t+2's 4 loads in flight, so tile t+1 is
        // resident for every wave crossing the barrier.
        asm volatile("s_waitcnt lgkmcnt(0)" ::: "memory");
        if (do_stage) asm volatile("s_waitcnt vmcnt(4)" ::: "memory");
        else          asm volatile("s_waitcnt vmcnt(0)" ::: "memory");
        __builtin_amdgcn_s_barrier();

        cur = (cur == 2) ? 0 : cur + 1;
        stg = (stg == 2) ? 0 : stg + 1;
    }

    // Epilogue: C/D layout col = lane&15, row = (lane>>4)*4 + reg
#pragma unroll
    for (int n = 0; n < 4; ++n) {
        int gc = bcol + wcN + n * 16 + lr;
        float ds = dsp[gc];
        int qb = qbp[gc];
#pragma unroll
        for (int m = 0; m < 8; ++m) {
            int gr0 = brow + wrM + m * 16 + ls * 4;
#pragma unroll
            for (int r = 0; r < 4; ++r) {
                C[(long)(gr0 + r) * N_DIM + gc] = (float)(acc[m][n][r] + qb) * ds;
            }
        }
    }
}

// ---------------------------------------------------------------------------
extern "C" void kernel_launch(void* const* d_in, const int* in_sizes, int n_in,
                              void* d_out, int out_size, void* d_ws, size_t ws_size,
                              hipStream_t stream)
{
    (void)in_sizes; (void)n_in; (void)out_size; (void)ws_size;
    const float* x   = (const float*)d_in[0];
    const int*   w   = (const int*)d_in[1];
    const float* is  = (const float*)d_in[2];
    const int*   io  = (const int*)d_in[3];
    const float* dq  = (const float*)d_in[4];
    const int*   qb  = (const int*)d_in[5];
    const int*   idx = (const int*)d_in[6];
    float* out = (float*)d_out;

    int8_t* xq  = (int8_t*)d_ws;                           // 33554432 B
    int8_t* bp  = xq + (size_t)M_DIM * K_DIM;              // 16777216 B
    float*  dsp = (float*)(bp + (size_t)N_DIM * K_DIM);    // 16384 B
    int*    qbp = (int*)(dsp + N_DIM);                     // 16384 B

    long quant_blocks = ((long)M_DIM * K_DIM) / 16 / 256;  // 8192
    quant_x_kernel<<<(int)quant_blocks, 256, 0, stream>>>(x, is, io, xq);
    pack_w_kernel<<<N_DIM, 256, 0, stream>>>(w, idx, dq, qb, bp, dsp, qbp);
    gemm_i8_kernel<<<(M_DIM / BM) * (N_DIM / BN), 512, 0, stream>>>(xq, bp, dsp, qbp, out);
}

// Round 7
// 197.513 us; speedup vs baseline: 1.0449x; 1.0029x over previous
//
#include <hip/hip_runtime.h>
#include <hip/hip_bf16.h>
#include <stdint.h>

#define M_DIM 8192
#define K_DIM 4096
#define N_DIM 4096

#define BM 256
#define BN 256
#define BKB 64              // K-bytes (=i8 elems) per tile
#define NT (K_DIM / BKB)    // 64 K-tiles
#define ATILE (BM * BKB)    // 16384 B
#define TBYTES (ATILE + BN * BKB)   // 32768 B per K-tile buffer

typedef int i32x4 __attribute__((ext_vector_type(4)));

// ---------------------------------------------------------------------------
// Kernel 1: per-tensor activation quantization f32 -> i8 (unchanged, passing)
// ---------------------------------------------------------------------------
__global__ __launch_bounds__(256) void quant_x_kernel(
    const float* __restrict__ x, const float* __restrict__ scale_p,
    const int* __restrict__ off_p, int8_t* __restrict__ xq)
{
    const float s = scale_p[0];
    const float off = (float)off_p[0];
    long base = ((long)blockIdx.x * 256 + threadIdx.x) * 16;
    const float4* xin = (const float4*)(x + base);
    float v[16];
    *(float4*)(v + 0)  = xin[0];
    *(float4*)(v + 4)  = xin[1];
    *(float4*)(v + 8)  = xin[2];
    *(float4*)(v + 12) = xin[3];
    uint32_t pk[4];
#pragma unroll
    for (int g = 0; g < 4; ++g) {
        uint32_t p = 0;
#pragma unroll
        for (int j = 0; j < 4; ++j) {
            float q = rintf(v[g * 4 + j] / s) + off;
            q = fminf(fmaxf(q, -128.0f), 127.0f);
            int qi = (int)q;
            p |= ((uint32_t)(qi & 0xff)) << (8 * j);
        }
        pk[g] = p;
    }
    uint4 o; o.x = pk[0]; o.y = pk[1]; o.z = pk[2]; o.w = pk[3];
    *(uint4*)(xq + base) = o;
}

// ---------------------------------------------------------------------------
// Kernel 2: weight pack + permutation fold (unchanged, passing)
// ---------------------------------------------------------------------------
__global__ __launch_bounds__(256) void pack_w_kernel(
    const int* __restrict__ w, const int* __restrict__ index,
    const float* __restrict__ deq, const int* __restrict__ qb,
    int8_t* __restrict__ bp, float* __restrict__ dsp, int* __restrict__ qbp)
{
    int j = blockIdx.x;
    int t = threadIdx.x;
    int src = index[j];
    const int4* wrow = (const int4*)(w + (long)src * K_DIM);
    uint32_t pk[4];
#pragma unroll
    for (int g = 0; g < 4; ++g) {
        int4 c = wrow[t * 4 + g];
        pk[g] = ((uint32_t)(c.x & 0xff)) | (((uint32_t)(c.y & 0xff)) << 8) |
                (((uint32_t)(c.z & 0xff)) << 16) | (((uint32_t)(c.w & 0xff)) << 24);
    }
    uint4 o; o.x = pk[0]; o.y = pk[1]; o.z = pk[2]; o.w = pk[3];
    *(uint4*)(bp + (long)j * K_DIM + t * 16) = o;
    if (t == 0) { dsp[j] = deq[src]; qbp[j] = qb[src]; }
}

// ---------------------------------------------------------------------------
// Kernel 3: 256x256 int8 GEMM, ring-of-3 LDS as THREE DISTINCT static
// __shared__ arrays (tb0/tb1/tb2) with the main loop statically unrolled x3,
// so the compiler can PROVE ds_read(cur) does not alias global_load_lds
// write(stg). R2-R6 used lds[3][...] with runtime indices: SIInsertWaitcnts
// could not disambiguate and inserted a hidden vmcnt(0) before every tile's
// fragment reads, serializing DS / VMEM / MFMA pipes (counters: exactly
// additive 1306 matrix + ~1170 LDS + ~300 overhead = 2794 cyc/tile).
// Per tile: {12 ds_read_b128 (reads first) -> 4 global_load_lds of t+2 ->
// 32 MFMA with compiler-counted lgkm interleave} -> lgkmcnt(0) (free; pins
// buffer-reuse invariant) -> vmcnt(4) (counted: t+2's loads stay in flight)
// -> raw s_barrier (no implicit fence -> no compiler vmcnt(0)).
// ---------------------------------------------------------------------------
__device__ __forceinline__ void gload_lds16(const int8_t* g, int8_t* l)
{
    __builtin_amdgcn_global_load_lds(
        (const __attribute__((address_space(1))) uint32_t*)g,
        (__attribute__((address_space(3))) uint32_t*)l, 16, 0, 0);
}

__global__ __launch_bounds__(512, 2) void gemm_i8_kernel(
    const int8_t* __restrict__ A, const int8_t* __restrict__ B,
    const float* __restrict__ dsp, const int* __restrict__ qbp,
    float* __restrict__ C)
{
    __shared__ int8_t tb0[TBYTES];   // ring slot 0 (A | B halves)
    __shared__ int8_t tb1[TBYTES];   // ring slot 1
    __shared__ int8_t tb2[TBYTES];   // ring slot 2   -> 96 KB total

    // XCD-aware bijective swizzle (grid = 512, divisible by 8)
    int bid = blockIdx.x;
    int swz = (bid & 7) * (gridDim.x >> 3) + (bid >> 3);
    int bm = swz & 31;              // M/BM = 32
    int bn = swz >> 5;              // N/BN = 16
    int brow = bm * BM, bcol = bn * BN;

    int t = threadIdx.x;
    int wv = t >> 6;
    int l  = t & 63;
    int lr = l & 15;                // row within 16x16 fragment
    int ls = l >> 4;                // logical 16B k-slot
    int wrM = (wv >> 2) * 128;      // wave row offset (2 M-waves)
    int wcN = (wv & 3) * 64;        // wave col offset (4 N-waves)
    int pslot = ls ^ ((lr >> 1) & 3);   // swizzled physical slot (lane-const)

    // ds_read byte offsets within a K-tile buffer (A half then B half)
    int aoff[8], boff[4];
#pragma unroll
    for (int m = 0; m < 8; ++m)
        aoff[m] = (wrM + m * 16 + lr) * BKB + pslot * 16;
#pragma unroll
    for (int n = 0; n < 4; ++n)
        boff[n] = ATILE + (wcN + n * 16 + lr) * BKB + pslot * 16;

    // Staging: 2 A-chunks + 2 B-chunks (16B each) per thread per K-tile.
    // Linear LDS dest; global source pre-swizzled (slot = (ca&3)^((row>>1)&3)).
    int ca0 = t, ca1 = 512 + t;
    int r0 = ca0 >> 2, r1 = ca1 >> 2;
    const int8_t* sa0 = A + (long)(brow + r0) * K_DIM + ((ca0 & 3) ^ ((r0 >> 1) & 3)) * 16;
    const int8_t* sa1 = A + (long)(brow + r1) * K_DIM + ((ca1 & 3) ^ ((r1 >> 1) & 3)) * 16;
    const int8_t* sb0 = B + (long)(bcol + r0) * K_DIM + ((ca0 & 3) ^ ((r0 >> 1) & 3)) * 16;
    const int8_t* sb1 = B + (long)(bcol + r1) * K_DIM + ((ca1 & 3) ^ ((r1 >> 1) & 3)) * 16;
    const int da0 = ca0 * 16, da1 = ca1 * 16;
    const int db0 = ATILE + ca0 * 16, db1 = ATILE + ca1 * 16;

#define STAGE4(STG) do { \
        gload_lds16(sa0, (STG) + da0); \
        gload_lds16(sa1, (STG) + da1); \
        gload_lds16(sb0, (STG) + db0); \
        gload_lds16(sb1, (STG) + db1); \
        sa0 += BKB; sa1 += BKB; sb0 += BKB; sb1 += BKB; \
    } while (0)

// One K-tile: reads from CUR (lexically distinct array), prefetch t+2 into
// STG, MFMA cluster (compiler interleaves counted lgkm waits), tile-end
// counted vmcnt + raw barrier. No fence between reads and MFMAs.
#define GEMM_TILE(CUR, STG, KT) do { \
        i32x4 af[8], bf[4]; \
        _Pragma("unroll") \
        for (int n = 0; n < 4; ++n) bf[n] = *(const i32x4*)((CUR) + boff[n]); \
        _Pragma("unroll") \
        for (int m = 0; m < 8; ++m) af[m] = *(const i32x4*)((CUR) + aoff[m]); \
        const bool _st = (KT) + 2 < NT; \
        if (_st) STAGE4(STG); \
        _Pragma("unroll") \
        for (int m = 0; m < 8; ++m) \
        _Pragma("unroll") \
        for (int n = 0; n < 4; ++n) \
            acc[m][n] = __builtin_amdgcn_mfma_i32_16x16x64_i8( \
                af[m], bf[n], acc[m][n], 0, 0, 0); \
        asm volatile("s_waitcnt lgkmcnt(0)" ::: "memory"); \
        if (_st) asm volatile("s_waitcnt vmcnt(4)" ::: "memory"); \
        else     asm volatile("s_waitcnt vmcnt(0)" ::: "memory"); \
        __builtin_amdgcn_s_barrier(); \
    } while (0)

    // Prologue: stage tiles 0 -> tb0, 1 -> tb1
    STAGE4(tb0);
    STAGE4(tb1);
    asm volatile("s_waitcnt vmcnt(4)" ::: "memory");   // tile 0 resident
    __builtin_amdgcn_s_barrier();

    i32x4 acc[8][4] = {};

    // Main loop: 63 tiles = 21 iterations x ring period 3. Static buffer
    // names everywhere -> full alias disambiguation.
    for (int kt = 0; kt < 63; kt += 3) {
        GEMM_TILE(tb0, tb2, kt);
        GEMM_TILE(tb1, tb0, kt + 1);
        GEMM_TILE(tb2, tb1, kt + 2);
    }
    // Tail tile 63 (cur = tb0, no stage, no trailing barrier needed)
    {
        i32x4 af[8], bf[4];
#pragma unroll
        for (int n = 0; n < 4; ++n) bf[n] = *(const i32x4*)(tb0 + boff[n]);
#pragma unroll
        for (int m = 0; m < 8; ++m) af[m] = *(const i32x4*)(tb0 + aoff[m]);
#pragma unroll
        for (int m = 0; m < 8; ++m)
#pragma unroll
            for (int n = 0; n < 4; ++n)
                acc[m][n] = __builtin_amdgcn_mfma_i32_16x16x64_i8(
                    af[m], bf[n], acc[m][n], 0, 0, 0);
    }

#undef STAGE4
#undef GEMM_TILE

    // Epilogue: C/D layout col = lane&15, row = (lane>>4)*4 + reg
#pragma unroll
    for (int n = 0; n < 4; ++n) {
        int gc = bcol + wcN + n * 16 + lr;
        float ds = dsp[gc];
        int qb = qbp[gc];
#pragma unroll
        for (int m = 0; m < 8; ++m) {
            int gr0 = brow + wrM + m * 16 + ls * 4;
#pragma unroll
            for (int r = 0; r < 4; ++r) {
                C[(long)(gr0 + r) * N_DIM + gc] = (float)(acc[m][n][r] + qb) * ds;
            }
        }
    }
}

// ---------------------------------------------------------------------------
extern "C" void kernel_launch(void* const* d_in, const int* in_sizes, int n_in,
                              void* d_out, int out_size, void* d_ws, size_t ws_size,
                              hipStream_t stream)
{
    (void)in_sizes; (void)n_in; (void)out_size; (void)ws_size;
    const float* x   = (const float*)d_in[0];
    const int*   w   = (const int*)d_in[1];
    const float* is  = (const float*)d_in[2];
    const int*   io  = (const int*)d_in[3];
    const float* dq  = (const float*)d_in[4];
    const int*   qb  = (const int*)d_in[5];
    const int*   idx = (const int*)d_in[6];
    float* out = (float*)d_out;

    int8_t* xq  = (int8_t*)d_ws;                           // 33554432 B
    int8_t* bp  = xq + (size_t)M_DIM * K_DIM;              // 16777216 B
    float*  dsp = (float*)(bp + (size_t)N_DIM * K_DIM);    // 16384 B
    int*    qbp = (int*)(dsp + N_DIM);                     // 16384 B

    long quant_blocks = ((long)M_DIM * K_DIM) / 16 / 256;  // 8192
    quant_x_kernel<<<(int)quant_blocks, 256, 0, stream>>>(x, is, io, xq);
    pack_w_kernel<<<N_DIM, 256, 0, stream>>>(w, idx, dq, qb, bp, dsp, qbp);
    gemm_i8_kernel<<<(M_DIM / BM) * (N_DIM / BN), 512, 0, stream>>>(xq, bp, dsp, qbp, out);
}